// Round 2
// baseline (173.057 us; speedup 1.0000x reference)
//
#include <hip/hip_runtime.h>

// VDP dropout:
//   keep      = (u >= 0.1f)
//   mu_out    = mu_in    * keep / 0.9
//   Sigma_out = Sigma_in * keep / 768     (D = last-dim size)
//
// N = 64*197*768 = 9,682,944 fp32 elements. Memory-bound: ~194 MB total.
// R1: 4 float4 per thread (block-strided, fully coalesced) to deepen the
// VMEM queue — 12 independent loads in flight per thread vs 3 in R0.
// n4 = 2,420,736 = 2364 blocks * 1024 float4/block exactly (no tail).

#define DROP_PROP 0.1f
#define UNROLL 4

__global__ __launch_bounds__(256) void vdp_dropout_kernel(
    const float4* __restrict__ mu_in,
    const float4* __restrict__ sigma_in,
    const float4* __restrict__ u,
    float4* __restrict__ mu_out,
    float4* __restrict__ sigma_out,
    int n4)
{
    const float inv_keep = 1.0f / (1.0f - DROP_PROP);   // 1/0.9
    const float inv_d    = 1.0f / 768.0f;

    const int base = blockIdx.x * (256 * UNROLL) + threadIdx.x;

    float4 uu[UNROLL], m[UNROLL], s[UNROLL];
    int idx[UNROLL];

    // Issue all loads back-to-back: 3*UNROLL independent VMEM ops in flight.
    #pragma unroll
    for (int k = 0; k < UNROLL; ++k) {
        idx[k] = base + k * 256;
        bool ok = idx[k] < n4;
        int ii = ok ? idx[k] : 0;
        uu[k] = u[ii];
        m[k]  = mu_in[ii];
        s[k]  = sigma_in[ii];
    }

    #pragma unroll
    for (int k = 0; k < UNROLL; ++k) {
        if (idx[k] >= n4) continue;
        float4 mo, so;
        mo.x = (uu[k].x >= DROP_PROP) ? m[k].x * inv_keep : 0.0f;
        mo.y = (uu[k].y >= DROP_PROP) ? m[k].y * inv_keep : 0.0f;
        mo.z = (uu[k].z >= DROP_PROP) ? m[k].z * inv_keep : 0.0f;
        mo.w = (uu[k].w >= DROP_PROP) ? m[k].w * inv_keep : 0.0f;

        so.x = (uu[k].x >= DROP_PROP) ? s[k].x * inv_d : 0.0f;
        so.y = (uu[k].y >= DROP_PROP) ? s[k].y * inv_d : 0.0f;
        so.z = (uu[k].z >= DROP_PROP) ? s[k].z * inv_d : 0.0f;
        so.w = (uu[k].w >= DROP_PROP) ? s[k].w * inv_d : 0.0f;

        mu_out[idx[k]]    = mo;
        sigma_out[idx[k]] = so;
    }
}

extern "C" void kernel_launch(void* const* d_in, const int* in_sizes, int n_in,
                              void* d_out, int out_size, void* d_ws, size_t ws_size,
                              hipStream_t stream)
{
    const float* mu_in    = (const float*)d_in[0];
    const float* sigma_in = (const float*)d_in[1];
    const float* u        = (const float*)d_in[2];

    const int n = in_sizes[0];          // 9,682,944
    float* mu_out    = (float*)d_out;           // first n elements
    float* sigma_out = (float*)d_out + n;       // next n elements

    const int n4 = n / 4;               // 2,420,736
    const int block = 256;
    const int per_block = block * UNROLL;       // 1024 float4 per block
    const int grid = (n4 + per_block - 1) / per_block;   // 2364

    vdp_dropout_kernel<<<grid, block, 0, stream>>>(
        (const float4*)mu_in, (const float4*)sigma_in, (const float4*)u,
        (float4*)mu_out, (float4*)sigma_out, n4);
}

// Round 4
// 170.780 us; speedup vs baseline: 1.0133x; 1.0133x over previous
//
#include <hip/hip_runtime.h>

// VDP dropout:
//   keep      = (u >= 0.1f)
//   mu_out    = mu_in    * keep / 0.9
//   Sigma_out = Sigma_in * keep / 768     (D = last-dim size)
//
// N = 64*197*768 = 9,682,944 fp32. Memory-bound, ~194 MB logical traffic.
// R3: R0 structure + NONTEMPORAL stores (outputs never re-read -> bypass L2
// alloc/dirty-writeback churn on the 77 MB write stream). Store via native
// ext_vector_type — __builtin_nontemporal_store rejects HIP_vector_type.
// Loads stay cached (L3 serves ~half the input reads: FETCH 56.7 vs 113 MB).

#define DROP_PROP 0.1f

typedef float vfloat4 __attribute__((ext_vector_type(4)));

__global__ __launch_bounds__(256) void vdp_dropout_kernel(
    const vfloat4* __restrict__ mu_in,
    const vfloat4* __restrict__ sigma_in,
    const vfloat4* __restrict__ u,
    vfloat4* __restrict__ mu_out,
    vfloat4* __restrict__ sigma_out,
    int n4)
{
    const float inv_keep = 1.0f / (1.0f - DROP_PROP);   // 1/0.9
    const float inv_d    = 1.0f / 768.0f;

    int i = blockIdx.x * blockDim.x + threadIdx.x;
    if (i >= n4) return;

    vfloat4 uu = u[i];
    vfloat4 m  = mu_in[i];
    vfloat4 s  = sigma_in[i];

    vfloat4 mo, so;
    mo.x = (uu.x >= DROP_PROP) ? m.x * inv_keep : 0.0f;
    mo.y = (uu.y >= DROP_PROP) ? m.y * inv_keep : 0.0f;
    mo.z = (uu.z >= DROP_PROP) ? m.z * inv_keep : 0.0f;
    mo.w = (uu.w >= DROP_PROP) ? m.w * inv_keep : 0.0f;

    so.x = (uu.x >= DROP_PROP) ? s.x * inv_d : 0.0f;
    so.y = (uu.y >= DROP_PROP) ? s.y * inv_d : 0.0f;
    so.z = (uu.z >= DROP_PROP) ? s.z * inv_d : 0.0f;
    so.w = (uu.w >= DROP_PROP) ? s.w * inv_d : 0.0f;

    __builtin_nontemporal_store(mo, &mu_out[i]);
    __builtin_nontemporal_store(so, &sigma_out[i]);
}

extern "C" void kernel_launch(void* const* d_in, const int* in_sizes, int n_in,
                              void* d_out, int out_size, void* d_ws, size_t ws_size,
                              hipStream_t stream)
{
    const float* mu_in    = (const float*)d_in[0];
    const float* sigma_in = (const float*)d_in[1];
    const float* u        = (const float*)d_in[2];

    const int n = in_sizes[0];          // 9,682,944
    float* mu_out    = (float*)d_out;           // first n elements
    float* sigma_out = (float*)d_out + n;       // next n elements

    const int n4 = n / 4;               // 2,420,736
    const int block = 256;
    const int grid = (n4 + block - 1) / block;  // 9456

    vdp_dropout_kernel<<<grid, block, 0, stream>>>(
        (const vfloat4*)mu_in, (const vfloat4*)sigma_in, (const vfloat4*)u,
        (vfloat4*)mu_out, (vfloat4*)sigma_out, n4);
}